// Round 1
// baseline (79.648 us; speedup 1.0000x reference)
//
#include <hip/hip_runtime.h>

// FingerprintPool: B=64, A=32, C=64, SEG_LENS=(1,167,512), F_fp=679.
// Math reduction (biases cancel; max-subtraction dropped — scores are O(1)):
//   ed_i[a] = exp(x[a]·w_inner_i); fe_i[a] = ed_i[a]·(x[a]·w_inter_i)
//   per column l (hit mask m): Z = sum_hit ed, u_l = exp((sum_hit fe)/Z), cf_l = u_l/Z
//   H_i[a] = sum_{l in seg i, hit(l,a)} cf_l ;  S_i = sum_{l in seg i} u_l
//   out[c] = sum_a x[a][c] * sum_i ed_i[a]*H_i[a]/S_i
//
// R7: parallelism fix. The single-kernel version ran 64 blocks -> 64/256 CUs
// busy (Occupancy 8.5%), latency-bound at ~36 µs. Split each batch's 680
// columns across JB=8 blocks (512 blocks, 256 thr), partial H/S written to
// disjoint d_ws slots (no atomics, no memset needed — every slot consumed by
// the finish kernel is rewritten each iteration, so ws poison is harmless).
// Tiny 64-block finish kernel folds partials + computes the output GEMV.

constexpr int NB   = 64;
constexpr int NA   = 32;
constexpr int NC   = 64;
constexpr int NFP  = 679;   // fp columns (without the implicit ones column)
constexpr int LTOT = 680;   // 1 + 167 + 512
constexpr int S2   = 168;   // seg2 start (seg0 = {0}, seg1 = [1,168))
constexpr int JB   = 8;     // column-blocks per batch
constexpr int CPB  = LTOT / JB;  // 85 columns per block
constexpr int NT1  = 256;   // threads per k1 block (4 waves)
constexpr int NCHK1 = 8;    // scan chunks in k1
constexpr int CHKW1 = (CPB + NCHK1 - 1) / NCHK1;  // 11
constexpr int NT2  = 128;   // threads per k2 block

// ws layout per batch (floats):
//   [0,96)           ed  (i*32+a), written by j==0 block
//   [96, 96+JB*96)   Hpart[j][i*32+a]
//   [864, 864+JB*4)  Spart[j][i]  (i<3 used)
constexpr int WS_ED = 0;
constexpr int WS_H  = 96;
constexpr int WS_S  = 96 + JB * 96;   // 864
constexpr int WSB   = WS_S + JB * 4;  // 896 floats per batch

__device__ __forceinline__ int seg_of(int l) {
    return (l >= S2) ? 2 : ((l >= 1) ? 1 : 0);
}

__global__ __launch_bounds__(NT1) void fpool_k1(
    const float* __restrict__ x,        // (2048, 64)
    const int*   __restrict__ fp,       // (2048, 679)
    const float* __restrict__ w_inner,  // (3, 64)
    const float* __restrict__ w_inter,  // (3, 64)
    float*       __restrict__ ws)
{
    __shared__ float    x_s[NA][NC + 1];
    __shared__ float    w_s[6][NC];
    __shared__ float    ed_s[3][NA];
    __shared__ float    fe_s[3][NA];
    __shared__ unsigned mask_s[CPB];
    __shared__ float    u_s[CPB];
    __shared__ float    cf_s[CPB];
    __shared__ float    part_s[NCHK1][96];
    __shared__ float    pu_s[NCHK1][4];

    const int tid = threadIdx.x;
    const int b   = blockIdx.x >> 3;   // batch
    const int j   = blockIdx.x & 7;    // column-block within batch
    const int l0  = j * CPB;

    // ---- issue loads in first-use order: w, x, fp ----
    const float wv0 = (tid < 192) ? w_inner[tid] : w_inter[tid - 192];
    float wv1 = 0.f;
    if (tid < 128) wv1 = w_inter[64 + tid];

    const float* xb = x + (size_t)b * NA * NC;
    float xr[8];
    #pragma unroll
    for (int k = 0; k < 8; ++k) xr[k] = xb[tid + k * NT1];

    const int l = l0 + tid;            // this thread's column if tid < CPB
    int v[NA];                         // fp row slice; mask built lazily
    if (tid < CPB && l >= 1) {
        const int* f = fp + (size_t)b * NA * NFP + (l - 1);
        #pragma unroll
        for (int a = 0; a < NA; ++a) v[a] = f[(size_t)a * NFP];
    }

    ((float*)w_s)[tid] = wv0;
    if (tid < 128) ((float*)w_s)[NT1 + tid] = wv1;
    #pragma unroll
    for (int k = 0; k < 8; ++k) {
        const int idx = tid + k * NT1;
        x_s[idx >> 6][idx & 63] = xr[k];
    }
    __syncthreads();

    // ---- phase 1: 96 dot-pairs -> ed, fe ----
    if (tid < 96) {
        const int i = tid >> 5, a = tid & 31;
        float dacc = 0.f, eacc = 0.f;
        #pragma unroll
        for (int c = 0; c < NC; ++c) {
            const float t = x_s[a][c];
            dacc += t * w_s[i][c];
            eacc += t * w_s[3 + i][c];
        }
        const float ed = __expf(dacc);
        ed_s[i][a] = ed;
        fe_s[i][a] = ed * eacc;
        if (j == 0) ws[(size_t)b * WSB + WS_ED + tid] = ed;  // k2 needs ed
    }
    __syncthreads();

    // ---- phase 2: per-column mask, Z, u, cf ----
    if (tid < CPB) {
        unsigned m = 0xFFFFFFFFu;
        if (l >= 1) {
            m = 0u;
            #pragma unroll
            for (int a = 0; a < NA; ++a) m |= (v[a] != 0) ? (1u << a) : 0u;
        }
        const int i = seg_of(l);
        float Z = 0.f, P = 0.f;
        #pragma unroll
        for (int a = 0; a < NA; ++a) {
            const float bit = (float)((m >> a) & 1u);
            Z += bit * ed_s[i][a];
            P += bit * fe_s[i][a];
        }
        const float invZ = __frcp_rn(Z);              // Z>0 whenever m!=0
        const float u    = m ? __expf(P * invZ) : 0.f;
        mask_s[tid] = m;
        u_s[tid]    = u;
        cf_s[tid]   = m ? (u * invZ) : 0.f;
    }
    __syncthreads();

    // ---- phase 3: H partials + S partials in one column scan ----
    {
        const int a = tid & 31, chunk = tid >> 5;
        const int ls = chunk * CHKW1;
        const int le = (ls + CHKW1 < CPB) ? ls + CHKW1 : CPB;
        float h0 = 0.f, h1 = 0.f, h2 = 0.f, su = 0.f;
        for (int ll = ls; ll < le; ++ll) {
            const float cf = cf_s[ll] * (float)((mask_s[ll] >> a) & 1u);
            const int   sg = seg_of(l0 + ll);
            if (sg == 2)      h2 += cf;
            else if (sg == 1) h1 += cf;
            else              h0 += cf;
            if (a < 3 && sg == a) su += u_s[ll];      // lanes 0..2: S_i partial
        }
        part_s[chunk][a]      = h0;
        part_s[chunk][32 + a] = h1;
        part_s[chunk][64 + a] = h2;
        if (a < 4) pu_s[chunk][a] = su;
    }
    __syncthreads();

    // ---- phase 4: reduce partials, write to ws slot (b, j) ----
    if (tid < 96) {
        float s = 0.f;
        #pragma unroll
        for (int c = 0; c < NCHK1; ++c) s += part_s[c][tid];
        ws[(size_t)b * WSB + WS_H + j * 96 + tid] = s;
    } else if (tid < 99) {
        const int i = tid - 96;
        float s = 0.f;
        #pragma unroll
        for (int c = 0; c < NCHK1; ++c) s += pu_s[c][i];
        ws[(size_t)b * WSB + WS_S + j * 4 + i] = s;
    }
}

__global__ __launch_bounds__(NT2) void fpool_k2(
    const float* __restrict__ x,
    const float* __restrict__ ws,
    float*       __restrict__ out)
{
    __shared__ float H_s[96];
    __shared__ float S_s[3];
    __shared__ float ed2_s[96];
    __shared__ float Gsum_s[NA];

    const int tid = threadIdx.x;
    const int b   = blockIdx.x;
    const float* wb = ws + (size_t)b * WSB;

    if (tid < 96) {
        float h = 0.f;
        #pragma unroll
        for (int jj = 0; jj < JB; ++jj) h += wb[WS_H + jj * 96 + tid];
        H_s[tid]   = h;
        ed2_s[tid] = wb[WS_ED + tid];
    } else if (tid < 99) {
        const int i = tid - 96;
        float s = 0.f;
        #pragma unroll
        for (int jj = 0; jj < JB; ++jj) s += wb[WS_S + jj * 4 + i];
        S_s[i] = s;
    }
    __syncthreads();

    if (tid < NA) {
        Gsum_s[tid] = ed2_s[tid]      * H_s[tid]      / S_s[0]
                    + ed2_s[32 + tid] * H_s[32 + tid] / S_s[1]
                    + ed2_s[64 + tid] * H_s[64 + tid] / S_s[2];
    }
    __syncthreads();

    if (tid < NC) {
        const float* xb = x + (size_t)b * NA * NC;
        float acc = 0.f;
        #pragma unroll
        for (int a = 0; a < NA; ++a) acc += Gsum_s[a] * xb[a * NC + tid];
        out[b * NC + tid] = acc;
    }
}

extern "C" void kernel_launch(void* const* d_in, const int* in_sizes, int n_in,
                              void* d_out, int out_size, void* d_ws, size_t ws_size,
                              hipStream_t stream) {
    const float* x       = (const float*)d_in[0];
    // d_in[1] = batch (unused), d_in[3] = fp_length (unused)
    const int*   fp      = (const int*)d_in[2];
    const float* w_inner = (const float*)d_in[4];
    // d_in[5] = b_inner (cancels in softmax)
    const float* w_inter = (const float*)d_in[6];
    // d_in[7] = b_inter (cancels in softmax)
    float* out = (float*)d_out;
    float* ws  = (float*)d_ws;

    fpool_k1<<<NB * JB, NT1, 0, stream>>>(x, fp, w_inner, w_inter, ws);
    fpool_k2<<<NB, NT2, 0, stream>>>(x, ws, out);
}

// Round 2
// 77.101 us; speedup vs baseline: 1.0330x; 1.0330x over previous
//
#include <hip/hip_runtime.h>

// FingerprintPool: B=64, A=32, C=64, SEG_LENS=(1,167,512), F_fp=679.
// Math reduction (biases cancel; max-subtraction dropped — scores are O(1),
// validated exact-at-bf16 in R5):
//   ed_i[a] = exp(x[a]·w_inner_i); fe_i[a] = ed_i[a]·(x[a]·w_inter_i)
//   per column l (hit mask m): Z = sum_hit ed, u_l = exp((sum_hit fe)/Z), cf_l = u_l/Z
//   H_i[a] = sum_{l in seg i, hit(l,a)} cf_l ;  S_i = sum_{l in seg i} u_l
//   out[c] = sum_a x[a][c] * sum_i ed_i[a]*H_i[a]/S_i
//
// R8: REVERT to the single-kernel R6 structure. R7's 8x-parallel 2-kernel
// split was the decisive experiment: dur_us 77.1 -> 79.6 (+2.5 us = one
// extra graph node), proving per-iteration time is dominated by the
// harness's 256 MiB d_ws poison fill (~41 us at 81-83% HBM peak, its own
// roofline) + per-node overhead, NOT kernel exec (<~3 us, invisible at 8x
// parallelism). Single kernel = minimum node count = measured best.

constexpr int NB   = 64;
constexpr int NA   = 32;
constexpr int NC   = 64;
constexpr int NFP  = 679;   // fp columns (without the implicit ones column)
constexpr int LTOT = 680;   // 1 + 167 + 512
constexpr int S2   = 168;   // seg2 start (seg0 = {0}, seg1 = [1,168))
constexpr int NT   = 1024;  // threads per block (16 waves)
constexpr int NCHK = 32;    // phase-5 chunks
constexpr int CHKW = 22;    // ceil(680/32): chunk 30 ends at 680, chunk 31 empty

__device__ __forceinline__ int seg_of(int l) {
    return (l >= S2) ? 2 : ((l >= 1) ? 1 : 0);
}

__global__ __launch_bounds__(NT) void fpool_kernel(
    const float* __restrict__ x,        // (2048, 64)
    const int*   __restrict__ fp,       // (2048, 679)
    const float* __restrict__ w_inner,  // (3, 64)
    const float* __restrict__ w_inter,  // (3, 64)
    float*       __restrict__ out)      // (64, 64)
{
    __shared__ float    x_s[NA][NC + 1];
    __shared__ float    w_s[6][NC];
    __shared__ float    ed_s[3][NA];
    __shared__ float    fe_s[3][NA];
    __shared__ unsigned mask_s[LTOT];
    __shared__ float    u_s[LTOT];
    __shared__ float    cf_s[LTOT];        // u_l / Z_l (0 for empty columns)
    __shared__ float    part_s[NCHK][96];  // H partials [chunk][i*32+a]
    __shared__ float    pu_s[NCHK][4];     // S partials [chunk][i]
    __shared__ float    H_s[96];
    __shared__ float    S_s[3];
    __shared__ float    Gsum_s[NA];

    const int tid = threadIdx.x;
    const int b   = blockIdx.x;
    const int l   = tid;

    // ---- issue loads in first-use order: w, x, fp ----
    float wv = 0.f;
    if (tid < 384) wv = (tid < 192) ? w_inner[tid] : w_inter[tid - 192];

    const float* xb = x + (size_t)b * NA * NC;
    const float  x0 = xb[tid];
    const float  x1 = xb[tid + NT];

    int v[NA];                              // fp row slice; mask built lazily
    if (l >= 1 && l < LTOT) {
        const int* f = fp + (size_t)b * NA * NFP + (l - 1);
        #pragma unroll
        for (int a = 0; a < NA; ++a) v[a] = f[(size_t)a * NFP];
    }

    if (tid < 384) ((float*)w_s)[tid] = wv;
    x_s[tid >> 6][tid & 63] = x0;
    { const int i1 = tid + NT; x_s[i1 >> 6][i1 & 63] = x1; }
    __syncthreads();

    // ---- phase 1: 96 dot-pairs -> ed, fe (no max-sub, no shuffles) ----
    if (tid < 96) {
        const int i = tid >> 5, a = tid & 31;
        float dacc = 0.f, eacc = 0.f;
        #pragma unroll
        for (int c = 0; c < NC; ++c) {
            const float t = x_s[a][c];
            dacc += t * w_s[i][c];
            eacc += t * w_s[3 + i][c];
        }
        const float ed = __expf(dacc);
        ed_s[i][a] = ed;
        fe_s[i][a] = ed * eacc;
    }
    __syncthreads();

    // ---- phase 3: per-column mask, Z, u, cf (fp regs drain here) ----
    if (l < LTOT) {
        unsigned m = 0xFFFFFFFFu;
        if (l >= 1) {
            m = 0u;
            #pragma unroll
            for (int a = 0; a < NA; ++a) m |= (v[a] != 0) ? (1u << a) : 0u;
        }
        const int i = seg_of(l);
        float Z = 0.f, P = 0.f;
        #pragma unroll
        for (int a = 0; a < NA; ++a) {
            const float bit = (float)((m >> a) & 1u);
            Z += bit * ed_s[i][a];
            P += bit * fe_s[i][a];
        }
        const float invZ = __frcp_rn(Z);              // Z>0 whenever m!=0
        const float u    = m ? __expf(P * invZ) : 0.f;
        mask_s[l] = m;
        u_s[l]    = u;
        cf_s[l]   = m ? (u * invZ) : 0.f;
    }
    __syncthreads();

    // ---- phase 5: H partials + S partials in one column scan ----
    {
        const int a = tid & 31, chunk = tid >> 5;
        const int ls = chunk * CHKW;
        const int le = (ls + CHKW < LTOT) ? ls + CHKW : LTOT;
        float h0 = 0.f, h1 = 0.f, h2 = 0.f, su = 0.f;
        for (int ll = ls; ll < le; ++ll) {
            const float cf = cf_s[ll] * (float)((mask_s[ll] >> a) & 1u);
            const int   sg = seg_of(ll);
            if (sg == 2)      h2 += cf;
            else if (sg == 1) h1 += cf;
            else              h0 += cf;
            if (a < 3 && sg == a) su += u_s[ll];      // lanes 0..2: S_i partial
        }
        part_s[chunk][a]      = h0;
        part_s[chunk][32 + a] = h1;
        part_s[chunk][64 + a] = h2;
        if (a < 3) pu_s[chunk][a] = su;
    }
    __syncthreads();

    // ---- phase 5b: reduce partials ----
    if (tid < 96) {
        float s = 0.f;
        #pragma unroll
        for (int c = 0; c < NCHK; ++c) s += part_s[c][tid];
        H_s[tid] = s;
    } else if (tid < 99) {
        const int i = tid - 96;
        float s = 0.f;
        #pragma unroll
        for (int c = 0; c < NCHK; ++c) s += pu_s[c][i];
        S_s[i] = s;
    }
    __syncthreads();

    // ---- phase 6: Gsum then output ----
    if (tid < NA) {
        Gsum_s[tid] = ed_s[0][tid] * H_s[tid]      / S_s[0]
                    + ed_s[1][tid] * H_s[32 + tid] / S_s[1]
                    + ed_s[2][tid] * H_s[64 + tid] / S_s[2];
    }
    __syncthreads();
    if (tid < NC) {
        float acc = 0.f;
        #pragma unroll
        for (int a = 0; a < NA; ++a) acc += Gsum_s[a] * x_s[a][tid];
        out[b * NC + tid] = acc;
    }
}

extern "C" void kernel_launch(void* const* d_in, const int* in_sizes, int n_in,
                              void* d_out, int out_size, void* d_ws, size_t ws_size,
                              hipStream_t stream) {
    const float* x       = (const float*)d_in[0];
    // d_in[1] = batch (unused), d_in[3] = fp_length (unused)
    const int*   fp      = (const int*)d_in[2];
    const float* w_inner = (const float*)d_in[4];
    // d_in[5] = b_inner (cancels in softmax)
    const float* w_inter = (const float*)d_in[6];
    // d_in[7] = b_inter (cancels in softmax)
    float* out = (float*)d_out;

    fpool_kernel<<<NB, NT, 0, stream>>>(x, fp, w_inner, w_inter, out);
}